// Round 7
// baseline (110.442 us; speedup 1.0000x reference)
//
#include <hip/hip_runtime.h>

// BilateralFilter3D 3x3x3, replicate pad, sigma_d=120, sigma_r=1.2
// (B,1,128,192,192) fp32.
//
// Round 7: per-wave stall arithmetic from r6: per z-step ~1300cyc compute +
// ~1000cyc exposed prefetch wait = 56% VALUBusy (measured, 3 rounds running),
// with ~1.7 waves/SIMD lockstep convoys providing no TLP cover. Busy time is
// already the math floor (~24us). Fix: 2 adjacent H-rows per thread -> the
// 3-row windows overlap, loads/step 9->12 rows for 2x the voxels
// (1.5 ld/voxel), compute per exposure doubles to ~2600cyc, two independent
// accumulator chains double ILP. Stall bound: 1000/3600 <= 28%.

typedef float f4 __attribute__((ext_vector_type(4)));

constexpr int Dd = 128;
constexpr int Hh = 192;
constexpr int Ww = 192;
constexpr int ZC = 4;                 // z-steps per thread

// quadratic minimax for exp(-t/(2*1.2^2)), t in [0,1]; spatial weights
// (dev <= 1.05e-4 from 1) folded out. Output shift < 5e-4 vs 1.69e-2 thr.
constexpr float A0 = 0.9998131f;
constexpr float A1 = -0.3437852f;
constexpr float A2 = 0.0508019f;

__device__ __forceinline__ f4 splat4(float v) { return (f4){v, v, v, v}; }

struct Row { f4 m; float lf, rf; };   // 4-voxel span + clamped edge scalars

__global__ __launch_bounds__(192, 2)
void bilateral3d_v7(const float* __restrict__ vol, float* __restrict__ out)
{
    const int t  = threadIdx.x;              // 0..47
    const int ty = threadIdx.y;              // 0..3
    const int h0 = blockIdx.x * 8 + ty * 2;  // even, 0..190; thread owns h0,h0+1
    const int z0 = blockIdx.y * ZC;          // 0,4,...,124
    const int b  = blockIdx.z;

    const size_t plane = (size_t)Hh * Ww;
    const float* __restrict__ base  = vol + (size_t)b * Dd * plane;
    float* __restrict__       obase = out + (size_t)b * Dd * plane;

    const int x0 = t << 2;
    const int lx = (x0 > 0) ? x0 - 1 : 0;           // replicate via address clamp
    const int rx = (x0 + 4 < Ww) ? x0 + 4 : Ww - 1;
    // 4 rows cover both outputs' windows: h0-1, h0, h0+1, h0+2 (clamped)
    const int yy[4] = { (h0 > 0) ? h0 - 1 : 0, h0, h0 + 1,
                        (h0 + 2 < Hh) ? h0 + 2 : Hh - 1 };

    Row P[3][4];   // [z-1, z, z+1][row]

    auto load_plane = [&](Row dst[4], int z) {
        const float* __restrict__ zb = base + (size_t)z * plane;
#pragma unroll
        for (int r = 0; r < 4; ++r) {
            const float* __restrict__ row = zb + (size_t)yy[r] * Ww;
            dst[r].m  = *(const f4*)(row + x0);
            dst[r].lf = row[lx];
            dst[r].rf = row[rx];
        }
    };

    load_plane(P[0], (z0 > 0) ? z0 - 1 : 0);
    load_plane(P[1], z0);
    load_plane(P[2], (z0 + 1 < Dd) ? z0 + 1 : Dd - 1);
    __builtin_amdgcn_sched_barrier(0);   // keep preamble loads batched

#define ACC(nv, cc, numv, denv)                                               \
    do {                                                                      \
        f4 _df = (nv) - (cc);                                                 \
        f4 _t  = _df * _df;                                                   \
        f4 _w  = __builtin_elementwise_fma(_t,                                \
                   __builtin_elementwise_fma(_t, splat4(A2), splat4(A1)),     \
                   splat4(A0));                                               \
        numv = __builtin_elementwise_fma(_w, (nv), numv);                     \
        denv = denv + _w;                                                     \
    } while (0)

#pragma unroll
    for (int dz = 0; dz < ZC; ++dz) {
        const int z = z0 + dz;

        // prefetch plane z+2 for the NEXT step; pinned above this step's
        // ~2600-cycle compute by the sched_barrier.
        Row N[4];
        load_plane(N, (z + 2 < Dd) ? z + 2 : Dd - 1);
        __builtin_amdgcn_sched_barrier(0);

        const f4 c0 = P[1][1].m;   // center row h0
        const f4 c1 = P[1][2].m;   // center row h0+1
        f4 num0 = splat4(0.0f), den0 = splat4(0.0f);
        f4 num1 = splat4(0.0f), den1 = splat4(0.0f);

#pragma unroll
        for (int p = 0; p < 3; ++p) {
#pragma unroll
            for (int r = 0; r < 4; ++r) {
                const f4 M  = P[p][r].m;
                const f4 nL = (f4){P[p][r].lf, M.x, M.y, M.z};   // dx=-1
                const f4 nR = (f4){M.y, M.z, M.w, P[p][r].rf};   // dx=+1
                if (r <= 2) {            // rows h0-1,h0,h0+1 -> output h0
                    ACC(nL, c0, num0, den0);
                    ACC(M,  c0, num0, den0);
                    ACC(nR, c0, num0, den0);
                }
                if (r >= 1) {            // rows h0,h0+1,h0+2 -> output h0+1
                    ACC(nL, c1, num1, den1);
                    ACC(M,  c1, num1, den1);
                    ACC(nR, c1, num1, den1);
                }
            }
        }

        // den >= ~19: reference clip(1e-8) is a no-op; fast rcp ~1ulp
        f4 r0, r1;
        r0.x = num0.x * __builtin_amdgcn_rcpf(den0.x);
        r0.y = num0.y * __builtin_amdgcn_rcpf(den0.y);
        r0.z = num0.z * __builtin_amdgcn_rcpf(den0.z);
        r0.w = num0.w * __builtin_amdgcn_rcpf(den0.w);
        r1.x = num1.x * __builtin_amdgcn_rcpf(den1.x);
        r1.y = num1.y * __builtin_amdgcn_rcpf(den1.y);
        r1.z = num1.z * __builtin_amdgcn_rcpf(den1.z);
        r1.w = num1.w * __builtin_amdgcn_rcpf(den1.w);
        float* __restrict__ orow = obase + (size_t)z * plane + (size_t)h0 * Ww + x0;
        *(f4*)orow        = r0;
        *(f4*)(orow + Ww) = r1;

        // rotate planes (pure register renaming under full unroll)
#pragma unroll
        for (int r = 0; r < 4; ++r) {
            P[0][r] = P[1][r];
            P[1][r] = P[2][r];
            P[2][r] = N[r];
        }
    }
#undef ACC
}

extern "C" void kernel_launch(void* const* d_in, const int* in_sizes, int n_in,
                              void* d_out, int out_size, void* d_ws, size_t ws_size,
                              hipStream_t stream)
{
    const float* vol = (const float*)d_in[0];
    float* out       = (float*)d_out;

    const int B = in_sizes[0] / (Dd * Hh * Ww);   // = 2

    dim3 grid(Hh / 8, Dd / ZC, B);   // (24, 32, 2) = 1536 blocks
    dim3 block(Ww / 4, 4, 1);        // 48 x 4 = 192 threads = 3 waves
    bilateral3d_v7<<<grid, block, 0, stream>>>(vol, out);
}